// Round 1
// baseline (353.222 us; speedup 1.0000x reference)
//
#include <hip/hip_runtime.h>
#include <hip/hip_bf16.h>

#define D 128
#define LOSS_MARGIN 0.2f
#define SPB 125   // 16-col steps per block => 2000 cols per slab

typedef __attribute__((ext_vector_type(8))) short bf16x8;
typedef __attribute__((ext_vector_type(4))) float f32x4;

static __device__ __forceinline__ unsigned short f2bf(float f) {
    unsigned u = __float_as_uint(f);
    unsigned r = (u + 0x7FFFu + ((u >> 16) & 1u)) >> 16;  // RNE
    return (unsigned short)r;
}

// Pass A: L2-normalize proxies -> bf16 ; convert embeddings -> bf16.
// One wave per row (128 floats = 2 per lane).
__global__ void prep_kernel(const float* __restrict__ prox,
                            const float* __restrict__ emb,
                            unsigned short* __restrict__ pn,
                            unsigned short* __restrict__ en,
                            int C, int B) {
    int wave = blockIdx.x * (blockDim.x >> 6) + (threadIdx.x >> 6);
    int lane = threadIdx.x & 63;
    if (wave >= C + B) return;
    const float* src;
    unsigned short* dst;
    bool donorm;
    if (wave < C) { src = prox + (size_t)wave * D; dst = pn + (size_t)wave * D; donorm = true; }
    else { int r = wave - C; src = emb + (size_t)r * D; dst = en + (size_t)r * D; donorm = false; }
    float2 v = *(const float2*)(src + lane * 2);
    float scale = 1.f;
    if (donorm) {  // wave-uniform branch
        float ss = v.x * v.x + v.y * v.y;
        #pragma unroll
        for (int m = 1; m < 64; m <<= 1) ss += __shfl_xor(ss, m);
        scale = rsqrtf(ss);
    }
    unsigned pack = (unsigned)f2bf(v.x * scale) | ((unsigned)f2bf(v.y * scale) << 16);
    *(unsigned*)(dst + lane * 2) = pack;
}

// Pass B: fused bf16 GEMM + per-row masked max over negatives.
// Block = 256 threads = 4 waves; wave owns 32 rows (2 x 16-row MFMA subtiles).
// Block covers 128 rows x 2000 cols (125 steps of 16 cols).
__global__ __launch_bounds__(256) void gemmmax_kernel(
        const unsigned short* __restrict__ en,
        const unsigned short* __restrict__ pn,
        const int* __restrict__ labels,
        unsigned int* __restrict__ minneg) {
    int lane = threadIdx.x & 63;
    int wid  = threadIdx.x >> 6;
    int wbase = blockIdx.x * 128 + wid * 32;
    int r16 = lane & 15;
    int g   = lane >> 4;

    // A fragments: lane l, slot j -> E[row = wbase+sub*16+(l&15)][k = k4*32 + (l>>4)*8 + j]
    bf16x8 a[2][4];
    #pragma unroll
    for (int s = 0; s < 2; ++s)
        #pragma unroll
        for (int k4 = 0; k4 < 4; ++k4)
            a[s][k4] = *(const bf16x8*)(en + (size_t)(wbase + s * 16 + r16) * D + k4 * 32 + g * 8);

    // labels for the 2x4 accumulator rows this lane owns (row = sub*16 + g*4 + i)
    int lab[2][4];
    #pragma unroll
    for (int s = 0; s < 2; ++s)
        #pragma unroll
        for (int i = 0; i < 4; ++i)
            lab[s][i] = labels[wbase + s * 16 + g * 4 + i];

    float rm[2][4];
    #pragma unroll
    for (int s = 0; s < 2; ++s)
        #pragma unroll
        for (int i = 0; i < 4; ++i) rm[s][i] = -1e30f;

    int col0 = blockIdx.y * (SPB * 16);
    int colg = col0 + r16;  // this lane's output column
    const unsigned short* pb = pn + (size_t)(col0 + r16) * D + g * 8;

    for (int step = 0; step < SPB; ++step) {
        bf16x8 b0 = *(const bf16x8*)(pb);
        bf16x8 b1 = *(const bf16x8*)(pb + 32);
        bf16x8 b2 = *(const bf16x8*)(pb + 64);
        bf16x8 b3 = *(const bf16x8*)(pb + 96);
        f32x4 acc0 = {0.f, 0.f, 0.f, 0.f};
        f32x4 acc1 = {0.f, 0.f, 0.f, 0.f};
        acc0 = __builtin_amdgcn_mfma_f32_16x16x32_bf16(a[0][0], b0, acc0, 0, 0, 0);
        acc1 = __builtin_amdgcn_mfma_f32_16x16x32_bf16(a[1][0], b0, acc1, 0, 0, 0);
        acc0 = __builtin_amdgcn_mfma_f32_16x16x32_bf16(a[0][1], b1, acc0, 0, 0, 0);
        acc1 = __builtin_amdgcn_mfma_f32_16x16x32_bf16(a[1][1], b1, acc1, 0, 0, 0);
        acc0 = __builtin_amdgcn_mfma_f32_16x16x32_bf16(a[0][2], b2, acc0, 0, 0, 0);
        acc1 = __builtin_amdgcn_mfma_f32_16x16x32_bf16(a[1][2], b2, acc1, 0, 0, 0);
        acc0 = __builtin_amdgcn_mfma_f32_16x16x32_bf16(a[0][3], b3, acc0, 0, 0, 0);
        acc1 = __builtin_amdgcn_mfma_f32_16x16x32_bf16(a[1][3], b3, acc1, 0, 0, 0);
        #pragma unroll
        for (int i = 0; i < 4; ++i) {
            float v0 = (colg == lab[0][i]) ? -1e30f : acc0[i];
            float v1 = (colg == lab[1][i]) ? -1e30f : acc1[i];
            rm[0][i] = fmaxf(rm[0][i], v0);
            rm[1][i] = fmaxf(rm[1][i], v1);
        }
        pb += 16 * D;
        colg += 16;
    }

    // reduce max across the 16 lanes of each row-group, then combine across blocks
    #pragma unroll
    for (int s = 0; s < 2; ++s)
        #pragma unroll
        for (int i = 0; i < 4; ++i) {
            float v = rm[s][i];
            v = fmaxf(v, __shfl_xor(v, 1));
            v = fmaxf(v, __shfl_xor(v, 2));
            v = fmaxf(v, __shfl_xor(v, 4));
            v = fmaxf(v, __shfl_xor(v, 8));
            if (r16 == 0) {
                int r = wbase + s * 16 + g * 4 + i;
                float md = fmaxf(2.f - 2.f * v, 0.f);  // non-negative -> uint order == float order
                atomicMin(minneg + r, __float_as_uint(md));
            }
        }
}

// Pass C: exact fp32 positive distance + per-row loss, accumulate sum.
__global__ void finalize_kernel(const float* __restrict__ emb,
                                const float* __restrict__ prox,
                                const int* __restrict__ labels,
                                const unsigned int* __restrict__ minneg,
                                float* __restrict__ accum, int B) {
    int wave = blockIdx.x * (blockDim.x >> 6) + (threadIdx.x >> 6);
    int lane = threadIdx.x & 63;
    if (wave >= B) return;
    int lab = labels[wave];
    float2 e = *(const float2*)(emb + (size_t)wave * D + lane * 2);
    float2 p = *(const float2*)(prox + (size_t)lab * D + lane * 2);
    float spp = p.x * p.x + p.y * p.y;
    float sep = e.x * p.x + e.y * p.y;
    #pragma unroll
    for (int m = 1; m < 64; m <<= 1) {
        spp += __shfl_xor(spp, m);
        sep += __shfl_xor(sep, m);
    }
    if (lane == 0) {
        float pos_sim = sep * rsqrtf(spp);
        float pos_dist = 2.f - 2.f * pos_sim;
        float mn = __uint_as_float(minneg[wave]);
        float loss = fmaxf(pos_dist + LOSS_MARGIN - mn, 0.f);
        atomicAdd(accum, loss);
    }
}

__global__ void writeout_kernel(const float* __restrict__ accum,
                                float* __restrict__ out, float invB) {
    out[0] = accum[0] * invB;
}

extern "C" void kernel_launch(void* const* d_in, const int* in_sizes, int n_in,
                              void* d_out, int out_size, void* d_ws, size_t ws_size,
                              hipStream_t stream) {
    const float* emb  = (const float*)d_in[0];
    const float* prox = (const float*)d_in[1];
    const int*   labels = (const int*)d_in[2];
    int B = in_sizes[0] / D;  // 2048
    int C = in_sizes[1] / D;  // 100000

    char* ws = (char*)d_ws;
    unsigned short* pn = (unsigned short*)ws;                       // C*D bf16 = 25.6 MB
    size_t offEN  = (size_t)C * D * 2;
    unsigned short* en = (unsigned short*)(ws + offEN);             // B*D bf16 = 0.5 MB
    size_t offMIN = offEN + (size_t)B * D * 2;
    unsigned int* minneg = (unsigned int*)(ws + offMIN);            // B u32
    size_t offACC = offMIN + (size_t)B * 4;
    float* accum = (float*)(ws + offACC);                           // 1 f32

    hipMemsetAsync(minneg, 0xFF, (size_t)B * 4, stream);  // +inf sentinel (uint max)
    hipMemsetAsync(accum, 0, 4, stream);

    int totalRows = C + B;
    prep_kernel<<<dim3((totalRows + 3) / 4), dim3(256), 0, stream>>>(prox, emb, pn, en, C, B);
    gemmmax_kernel<<<dim3(B / 128, C / (SPB * 16)), dim3(256), 0, stream>>>(en, pn, labels, minneg);
    finalize_kernel<<<dim3((B + 3) / 4), dim3(256), 0, stream>>>(emb, prox, labels, minneg, accum, B);
    writeout_kernel<<<dim3(1), dim3(1), 0, stream>>>(accum, (float*)d_out, 1.f / (float)B);
}

// Round 2
// 315.113 us; speedup vs baseline: 1.1209x; 1.1209x over previous
//
#include <hip/hip_runtime.h>
#include <hip/hip_bf16.h>

#define D 128
#define LOSS_MARGIN 0.2f
#define SPB 50   // 16-col steps per block => 800 cols per slab; C = 125 slabs * 800

typedef __attribute__((ext_vector_type(8))) short bf16x8;
typedef __attribute__((ext_vector_type(4))) float f32x4;

static __device__ __forceinline__ unsigned short f2bf(float f) {
    unsigned u = __float_as_uint(f);
    unsigned r = (u + 0x7FFFu + ((u >> 16) & 1u)) >> 16;  // RNE
    return (unsigned short)r;
}

// Pass A: L2-normalize proxies -> bf16 ; convert embeddings -> bf16.
// Two rows per wave (32 lanes/row, float4 loads, uint2 stores).
__global__ void prep_kernel(const float* __restrict__ prox,
                            const float* __restrict__ emb,
                            unsigned short* __restrict__ pn,
                            unsigned short* __restrict__ en,
                            int C, int B) {
    int wave = blockIdx.x * (blockDim.x >> 6) + (threadIdx.x >> 6);
    int lane = threadIdx.x & 63;
    int half = lane >> 5;   // which row of the pair
    int l32  = lane & 31;
    int row = wave * 2 + half;
    if (row >= C + B) return;
    const float* src;
    unsigned short* dst;
    bool donorm;
    if (row < C) { src = prox + (size_t)row * D; dst = pn + (size_t)row * D; donorm = true; }
    else { int r = row - C; src = emb + (size_t)r * D; dst = en + (size_t)r * D; donorm = false; }
    float4 v = *(const float4*)(src + l32 * 4);
    float scale = 1.f;
    if (donorm) {  // 32-lane-group uniform
        float ss = v.x * v.x + v.y * v.y + v.z * v.z + v.w * v.w;
        #pragma unroll
        for (int m = 1; m < 32; m <<= 1) ss += __shfl_xor(ss, m);
        scale = rsqrtf(ss);
    }
    uint2 pack;
    pack.x = (unsigned)f2bf(v.x * scale) | ((unsigned)f2bf(v.y * scale) << 16);
    pack.y = (unsigned)f2bf(v.z * scale) | ((unsigned)f2bf(v.w * scale) << 16);
    *(uint2*)(dst + l32 * 4) = pack;
}

// Pass B: fused bf16 GEMM + per-row masked max over negatives.
// Block = 4 waves; wave owns 32 rows (2 x 16-row MFMA subtiles); block = 128 rows.
// Column slab = SPB*16 = 800 cols. Register ping-pong prefetch of B fragments.
__global__ __launch_bounds__(256, 4) void gemmmax_kernel(
        const unsigned short* __restrict__ en,
        const unsigned short* __restrict__ pn,
        const int* __restrict__ labels,
        unsigned int* __restrict__ minneg) {
    int lane = threadIdx.x & 63;
    int wid  = threadIdx.x >> 6;
    int wbase = blockIdx.x * 128 + wid * 32;
    int r16 = lane & 15;
    int g   = lane >> 4;

    // A fragments: lane l, slot j -> E[row = wbase+sub*16+(l&15)][k = k4*32 + (l>>4)*8 + j]
    bf16x8 a[2][4];
    #pragma unroll
    for (int s = 0; s < 2; ++s)
        #pragma unroll
        for (int k4 = 0; k4 < 4; ++k4)
            a[s][k4] = *(const bf16x8*)(en + (size_t)(wbase + s * 16 + r16) * D + k4 * 32 + g * 8);

    // labels for the 2x4 accumulator rows this lane owns (row = sub*16 + g*4 + i)
    int lab[2][4];
    #pragma unroll
    for (int s = 0; s < 2; ++s)
        #pragma unroll
        for (int i = 0; i < 4; ++i)
            lab[s][i] = labels[wbase + s * 16 + g * 4 + i];

    float rm[2][4];
    #pragma unroll
    for (int s = 0; s < 2; ++s)
        #pragma unroll
        for (int i = 0; i < 4; ++i) rm[s][i] = -1e30f;

    int col0 = blockIdx.y * (SPB * 16);
    int colg = col0 + r16;  // this lane's output column
    const unsigned short* pb = pn + (size_t)(col0 + r16) * D + g * 8;

    bf16x8 b0[4], b1[4];
    #pragma unroll
    for (int j = 0; j < 4; ++j) b0[j] = *(const bf16x8*)(pb + 32 * j);
    pb += 16 * D;
    #pragma unroll
    for (int j = 0; j < 4; ++j) b1[j] = *(const bf16x8*)(pb + 32 * j);
    pb += 16 * D;

    for (int step = 0; step < SPB; step += 2) {
        // ---- even step: compute with b0 ----
        {
            f32x4 acc0 = {0.f, 0.f, 0.f, 0.f};
            f32x4 acc1 = {0.f, 0.f, 0.f, 0.f};
            #pragma unroll
            for (int j = 0; j < 4; ++j) {
                acc0 = __builtin_amdgcn_mfma_f32_16x16x32_bf16(a[0][j], b0[j], acc0, 0, 0, 0);
                acc1 = __builtin_amdgcn_mfma_f32_16x16x32_bf16(a[1][j], b0[j], acc1, 0, 0, 0);
            }
            // prefetch step+2 into b0 (pad rows keep the tail in bounds)
            #pragma unroll
            for (int j = 0; j < 4; ++j) b0[j] = *(const bf16x8*)(pb + 32 * j);
            pb += 16 * D;
            #pragma unroll
            for (int i = 0; i < 4; ++i) {
                float v0 = (colg == lab[0][i]) ? -1e30f : acc0[i];
                float v1 = (colg == lab[1][i]) ? -1e30f : acc1[i];
                rm[0][i] = fmaxf(rm[0][i], v0);
                rm[1][i] = fmaxf(rm[1][i], v1);
            }
            colg += 16;
        }
        // ---- odd step: compute with b1 ----
        {
            f32x4 acc0 = {0.f, 0.f, 0.f, 0.f};
            f32x4 acc1 = {0.f, 0.f, 0.f, 0.f};
            #pragma unroll
            for (int j = 0; j < 4; ++j) {
                acc0 = __builtin_amdgcn_mfma_f32_16x16x32_bf16(a[0][j], b1[j], acc0, 0, 0, 0);
                acc1 = __builtin_amdgcn_mfma_f32_16x16x32_bf16(a[1][j], b1[j], acc1, 0, 0, 0);
            }
            // prefetch step+3 into b1
            #pragma unroll
            for (int j = 0; j < 4; ++j) b1[j] = *(const bf16x8*)(pb + 32 * j);
            pb += 16 * D;
            #pragma unroll
            for (int i = 0; i < 4; ++i) {
                float v0 = (colg == lab[0][i]) ? -1e30f : acc0[i];
                float v1 = (colg == lab[1][i]) ? -1e30f : acc1[i];
                rm[0][i] = fmaxf(rm[0][i], v0);
                rm[1][i] = fmaxf(rm[1][i], v1);
            }
            colg += 16;
        }
    }

    // reduce max across the 16 lanes of each row-group, then combine across blocks
    #pragma unroll
    for (int s = 0; s < 2; ++s)
        #pragma unroll
        for (int i = 0; i < 4; ++i) {
            float v = rm[s][i];
            v = fmaxf(v, __shfl_xor(v, 1));
            v = fmaxf(v, __shfl_xor(v, 2));
            v = fmaxf(v, __shfl_xor(v, 4));
            v = fmaxf(v, __shfl_xor(v, 8));
            if (r16 == 0) {
                int r = wbase + s * 16 + g * 4 + i;
                float md = fmaxf(2.f - 2.f * v, 0.f);  // non-negative -> uint order == float order
                atomicMin(minneg + r, __float_as_uint(md));
            }
        }
}

// Pass C: exact fp32 positive distance + per-row loss, accumulate sum.
__global__ void finalize_kernel(const float* __restrict__ emb,
                                const float* __restrict__ prox,
                                const int* __restrict__ labels,
                                const unsigned int* __restrict__ minneg,
                                float* __restrict__ accum, int B) {
    int wave = blockIdx.x * (blockDim.x >> 6) + (threadIdx.x >> 6);
    int lane = threadIdx.x & 63;
    if (wave >= B) return;
    int lab = labels[wave];
    float2 e = *(const float2*)(emb + (size_t)wave * D + lane * 2);
    float2 p = *(const float2*)(prox + (size_t)lab * D + lane * 2);
    float spp = p.x * p.x + p.y * p.y;
    float sep = e.x * p.x + e.y * p.y;
    #pragma unroll
    for (int m = 1; m < 64; m <<= 1) {
        spp += __shfl_xor(spp, m);
        sep += __shfl_xor(sep, m);
    }
    if (lane == 0) {
        float pos_sim = sep * rsqrtf(spp);
        float pos_dist = 2.f - 2.f * pos_sim;
        float mn = __uint_as_float(minneg[wave]);
        float loss = fmaxf(pos_dist + LOSS_MARGIN - mn, 0.f);
        atomicAdd(accum, loss);
    }
}

__global__ void writeout_kernel(const float* __restrict__ accum,
                                float* __restrict__ out, float invB) {
    out[0] = accum[0] * invB;
}

extern "C" void kernel_launch(void* const* d_in, const int* in_sizes, int n_in,
                              void* d_out, int out_size, void* d_ws, size_t ws_size,
                              hipStream_t stream) {
    const float* emb  = (const float*)d_in[0];
    const float* prox = (const float*)d_in[1];
    const int*   labels = (const int*)d_in[2];
    int B = in_sizes[0] / D;  // 2048
    int C = in_sizes[1] / D;  // 100000

    char* ws = (char*)d_ws;
    unsigned short* pn = (unsigned short*)ws;                       // C*D bf16 = 25.6 MB
    size_t offEN  = (size_t)C * D * 2 + (size_t)32 * D * 2;         // +32 pad rows for tail prefetch
    unsigned short* en = (unsigned short*)(ws + offEN);             // B*D bf16 = 0.5 MB
    size_t offMIN = offEN + (size_t)B * D * 2;
    unsigned int* minneg = (unsigned int*)(ws + offMIN);            // B u32
    size_t offACC = offMIN + (size_t)B * 4;
    float* accum = (float*)(ws + offACC);                           // 1 f32

    hipMemsetAsync(minneg, 0xFF, (size_t)B * 4, stream);  // +inf sentinel (uint max)
    hipMemsetAsync(accum, 0, 4, stream);

    int totalRows = C + B;
    int prepWaves = (totalRows + 1) / 2;
    prep_kernel<<<dim3((prepWaves + 3) / 4), dim3(256), 0, stream>>>(prox, emb, pn, en, C, B);
    gemmmax_kernel<<<dim3(B / 128, C / (SPB * 16)), dim3(256), 0, stream>>>(en, pn, labels, minneg);
    finalize_kernel<<<dim3((B + 3) / 4), dim3(256), 0, stream>>>(emb, prox, labels, minneg, accum, B);
    writeout_kernel<<<dim3(1), dim3(1), 0, stream>>>(accum, (float*)d_out, 1.f / (float)B);
}

// Round 3
// 231.525 us; speedup vs baseline: 1.5256x; 1.3610x over previous
//
#include <hip/hip_runtime.h>
#include <hip/hip_bf16.h>

#define D 128
#define LOSS_MARGIN 0.2f
#define SPB 25            // 16-col steps per block => 400 cols per slab
#define SLAB (SPB * 16)   // 400; C = 250 slabs * 400

typedef __attribute__((ext_vector_type(8))) short bf16x8;
typedef __attribute__((ext_vector_type(4))) float f32x4;

static __device__ __forceinline__ unsigned short f2bf(float f) {
    unsigned u = __float_as_uint(f);
    unsigned r = (u + 0x7FFFu + ((u >> 16) & 1u)) >> 16;  // RNE
    return (unsigned short)r;
}

// Pass A: L2-normalize proxies -> bf16 ; convert embeddings -> bf16.
__global__ void prep_kernel(const float* __restrict__ prox,
                            const float* __restrict__ emb,
                            unsigned short* __restrict__ pn,
                            unsigned short* __restrict__ en,
                            int C, int B) {
    int wave = blockIdx.x * (blockDim.x >> 6) + (threadIdx.x >> 6);
    int lane = threadIdx.x & 63;
    int half = lane >> 5;
    int l32  = lane & 31;
    int row = wave * 2 + half;
    if (row >= C + B) return;
    const float* src;
    unsigned short* dst;
    bool donorm;
    if (row < C) { src = prox + (size_t)row * D; dst = pn + (size_t)row * D; donorm = true; }
    else { int r = row - C; src = emb + (size_t)r * D; dst = en + (size_t)r * D; donorm = false; }
    float4 v = *(const float4*)(src + l32 * 4);
    float scale = 1.f;
    if (donorm) {
        float ss = v.x * v.x + v.y * v.y + v.z * v.z + v.w * v.w;
        #pragma unroll
        for (int m = 1; m < 32; m <<= 1) ss += __shfl_xor(ss, m);
        scale = rsqrtf(ss);
    }
    uint2 pack;
    pack.x = (unsigned)f2bf(v.x * scale) | ((unsigned)f2bf(v.y * scale) << 16);
    pack.y = (unsigned)f2bf(v.z * scale) | ((unsigned)f2bf(v.w * scale) << 16);
    *(uint2*)(dst + l32 * 4) = pack;
}

// Pass B: fused bf16 GEMM + per-row max over negatives.
// Block = 4 waves; wave owns 64 rows (4 x 16-row MFMA subtiles); block = 256 rows.
// Column slab = 400 cols. Ping-pong register prefetch; positive-class masking
// hoisted out of the hot loop via a wave-uniform per-step bitmask.
__global__ __launch_bounds__(256, 3) void gemmmax_kernel(
        const unsigned short* __restrict__ en,
        const unsigned short* __restrict__ pn,
        const int* __restrict__ labels,
        unsigned int* __restrict__ minneg) {
    int lane = threadIdx.x & 63;
    int wid  = threadIdx.x >> 6;
    int wbase = blockIdx.x * 256 + wid * 64;
    int r16 = lane & 15;
    int g   = lane >> 4;
    int col0 = blockIdx.y * SLAB;

    // A fragments: lane l, slot j -> E[row = wbase+s4*16+(l&15)][k = k4*32 + (l>>4)*8 + j]
    bf16x8 a[4][4];
    #pragma unroll
    for (int s4 = 0; s4 < 4; ++s4)
        #pragma unroll
        for (int k4 = 0; k4 < 4; ++k4)
            a[s4][k4] = *(const bf16x8*)(en + (size_t)(wbase + s4 * 16 + r16) * D + k4 * 32 + g * 8);

    // Wave-uniform bitmask of steps containing a positive class for any of
    // this wave's 64 rows. Built per-lane from this lane's 16 rows, OR-reduced.
    unsigned bits = 0;
    #pragma unroll
    for (int s4 = 0; s4 < 4; ++s4)
        #pragma unroll
        for (int i = 0; i < 4; ++i) {
            int lb = labels[wbase + s4 * 16 + g * 4 + i];
            int pc = lb - col0;
            if (pc >= 0 && pc < SLAB) bits |= 1u << (pc >> 4);
        }
    #pragma unroll
    for (int m = 1; m < 64; m <<= 1) bits |= __shfl_xor(bits, m);
    unsigned sbits = __builtin_amdgcn_readfirstlane(bits);

    float rm[4][4];
    #pragma unroll
    for (int s4 = 0; s4 < 4; ++s4)
        #pragma unroll
        for (int i = 0; i < 4; ++i) rm[s4][i] = -1e30f;

    const unsigned short* pb0 = pn + (size_t)(col0 + r16) * D + g * 8;
    const unsigned short* pb1 = pb0 + 16 * D;

    bf16x8 b0[4], b1[4];
    #pragma unroll
    for (int j = 0; j < 4; ++j) b0[j] = *(const bf16x8*)(pb0 + 32 * j);
    pb0 += 32 * D;
    #pragma unroll
    for (int j = 0; j < 4; ++j) b1[j] = *(const bf16x8*)(pb1 + 32 * j);
    pb1 += 32 * D;

#define COMPUTE(BUF, STEP)                                                      \
    {                                                                           \
        f32x4 acc[4];                                                           \
        _Pragma("unroll")                                                       \
        for (int s4 = 0; s4 < 4; ++s4) acc[s4] = (f32x4){0.f, 0.f, 0.f, 0.f};   \
        _Pragma("unroll")                                                       \
        for (int j = 0; j < 4; ++j) {                                           \
            _Pragma("unroll")                                                   \
            for (int s4 = 0; s4 < 4; ++s4)                                      \
                acc[s4] = __builtin_amdgcn_mfma_f32_16x16x32_bf16(              \
                    a[s4][j], BUF[j], acc[s4], 0, 0, 0);                        \
        }                                                                       \
        if ((sbits >> (STEP)) & 1u) {  /* rare: positive in this step */        \
            int colg = col0 + (STEP) * 16 + r16;                                \
            _Pragma("unroll")                                                   \
            for (int s4 = 0; s4 < 4; ++s4)                                      \
                _Pragma("unroll")                                               \
                for (int i = 0; i < 4; ++i) {                                   \
                    int lb = labels[wbase + s4 * 16 + g * 4 + i];               \
                    float v = (colg == lb) ? -1e30f : acc[s4][i];               \
                    rm[s4][i] = fmaxf(rm[s4][i], v);                            \
                }                                                               \
        } else {                                                                \
            _Pragma("unroll")                                                   \
            for (int s4 = 0; s4 < 4; ++s4)                                      \
                _Pragma("unroll")                                               \
                for (int i = 0; i < 4; ++i)                                     \
                    rm[s4][i] = fmaxf(rm[s4][i], acc[s4][i]);                   \
        }                                                                       \
    }

    int s = 0;
    #pragma unroll 1
    for (; s < SPB - 3; s += 2) {
        COMPUTE(b0, s)
        #pragma unroll
        for (int j = 0; j < 4; ++j) b0[j] = *(const bf16x8*)(pb0 + 32 * j);
        pb0 += 32 * D;
        COMPUTE(b1, s + 1)
        #pragma unroll
        for (int j = 0; j < 4; ++j) b1[j] = *(const bf16x8*)(pb1 + 32 * j);
        pb1 += 32 * D;
    }
    // SPB odd: s == SPB-3 here. Steps s, s+1 in b0/b1; load final step into b0.
    COMPUTE(b0, s)
    #pragma unroll
    for (int j = 0; j < 4; ++j) b0[j] = *(const bf16x8*)(pb0 + 32 * j);
    COMPUTE(b1, s + 1)
    COMPUTE(b0, s + 2)
#undef COMPUTE

    // reduce max across the 16 lanes of each row-group, then combine across blocks
    #pragma unroll
    for (int s4 = 0; s4 < 4; ++s4)
        #pragma unroll
        for (int i = 0; i < 4; ++i) {
            float v = rm[s4][i];
            v = fmaxf(v, __shfl_xor(v, 1));
            v = fmaxf(v, __shfl_xor(v, 2));
            v = fmaxf(v, __shfl_xor(v, 4));
            v = fmaxf(v, __shfl_xor(v, 8));
            if (r16 == 0) {
                int r = wbase + s4 * 16 + g * 4 + i;
                float md = fmaxf(2.f - 2.f * v, 0.f);  // >=0 -> uint order == float order
                atomicMin(minneg + r, __float_as_uint(md));
            }
        }
}

// Pass C: exact fp32 positive distance + per-row loss, accumulate sum.
__global__ void finalize_kernel(const float* __restrict__ emb,
                                const float* __restrict__ prox,
                                const int* __restrict__ labels,
                                const unsigned int* __restrict__ minneg,
                                float* __restrict__ accum, int B) {
    int wave = blockIdx.x * (blockDim.x >> 6) + (threadIdx.x >> 6);
    int lane = threadIdx.x & 63;
    if (wave >= B) return;
    int lab = labels[wave];
    float2 e = *(const float2*)(emb + (size_t)wave * D + lane * 2);
    float2 p = *(const float2*)(prox + (size_t)lab * D + lane * 2);
    float spp = p.x * p.x + p.y * p.y;
    float sep = e.x * p.x + e.y * p.y;
    #pragma unroll
    for (int m = 1; m < 64; m <<= 1) {
        spp += __shfl_xor(spp, m);
        sep += __shfl_xor(sep, m);
    }
    if (lane == 0) {
        float pos_sim = sep * rsqrtf(spp);
        float pos_dist = 2.f - 2.f * pos_sim;
        float mn = __uint_as_float(minneg[wave]);
        float loss = fmaxf(pos_dist + LOSS_MARGIN - mn, 0.f);
        atomicAdd(accum, loss);
    }
}

__global__ void writeout_kernel(const float* __restrict__ accum,
                                float* __restrict__ out, float invB) {
    out[0] = accum[0] * invB;
}

extern "C" void kernel_launch(void* const* d_in, const int* in_sizes, int n_in,
                              void* d_out, int out_size, void* d_ws, size_t ws_size,
                              hipStream_t stream) {
    const float* emb  = (const float*)d_in[0];
    const float* prox = (const float*)d_in[1];
    const int*   labels = (const int*)d_in[2];
    int B = in_sizes[0] / D;  // 2048
    int C = in_sizes[1] / D;  // 100000

    char* ws = (char*)d_ws;
    unsigned short* pn = (unsigned short*)ws;                       // C*D bf16 = 25.6 MB
    size_t offEN  = (size_t)C * D * 2 + (size_t)32 * D * 2;         // +32 pad rows
    unsigned short* en = (unsigned short*)(ws + offEN);             // B*D bf16
    size_t offMIN = offEN + (size_t)B * D * 2;
    unsigned int* minneg = (unsigned int*)(ws + offMIN);            // B u32
    size_t offACC = offMIN + (size_t)B * 4;
    float* accum = (float*)(ws + offACC);                           // 1 f32

    hipMemsetAsync(minneg, 0xFF, (size_t)B * 4, stream);
    hipMemsetAsync(accum, 0, 4, stream);

    int totalRows = C + B;
    int prepWaves = (totalRows + 1) / 2;
    prep_kernel<<<dim3((prepWaves + 3) / 4), dim3(256), 0, stream>>>(prox, emb, pn, en, C, B);
    gemmmax_kernel<<<dim3(B / 256, C / SLAB), dim3(256), 0, stream>>>(en, pn, labels, minneg);
    finalize_kernel<<<dim3((B + 3) / 4), dim3(256), 0, stream>>>(emb, prox, labels, minneg, accum, B);
    writeout_kernel<<<dim3(1), dim3(1), 0, stream>>>(accum, (float*)d_out, 1.f / (float)B);
}

// Round 4
// 230.076 us; speedup vs baseline: 1.5352x; 1.0063x over previous
//
#include <hip/hip_runtime.h>
#include <hip/hip_bf16.h>

#define D 128
#define LOSS_MARGIN 0.2f
#define SPB 25            // 16-col steps per block => 400 cols per slab
#define SLAB (SPB * 16)   // 400; C = 250 slabs * 400
#define ROWG 8            // 2048 / 256 row-groups

typedef __attribute__((ext_vector_type(8))) short bf16x8;
typedef __attribute__((ext_vector_type(4))) float f32x4;

static __device__ __forceinline__ unsigned short f2bf(float f) {
    unsigned u = __float_as_uint(f);
    unsigned r = (u + 0x7FFFu + ((u >> 16) & 1u)) >> 16;  // RNE
    return (unsigned short)r;
}

// Pass A: L2-normalize proxies -> bf16 ; convert embeddings -> bf16.
// Also initializes minneg sentinels and the loss accumulator (replaces memsets).
__global__ void prep_kernel(const float* __restrict__ prox,
                            const float* __restrict__ emb,
                            unsigned short* __restrict__ pn,
                            unsigned short* __restrict__ en,
                            unsigned int* __restrict__ minneg,
                            float* __restrict__ accum,
                            int C, int B) {
    unsigned gtid = blockIdx.x * blockDim.x + threadIdx.x;
    if (gtid < (unsigned)B) minneg[gtid] = 0xFFFFFFFFu;
    if (gtid == 0) *accum = 0.f;

    int wave = blockIdx.x * (blockDim.x >> 6) + (threadIdx.x >> 6);
    int lane = threadIdx.x & 63;
    int half = lane >> 5;
    int l32  = lane & 31;
    int row = wave * 2 + half;
    if (row >= C + B) return;
    const float* src;
    unsigned short* dst;
    bool donorm;
    if (row < C) { src = prox + (size_t)row * D; dst = pn + (size_t)row * D; donorm = true; }
    else { int r = row - C; src = emb + (size_t)r * D; dst = en + (size_t)r * D; donorm = false; }
    float4 v = *(const float4*)(src + l32 * 4);
    float scale = 1.f;
    if (donorm) {
        float ss = v.x * v.x + v.y * v.y + v.z * v.z + v.w * v.w;
        #pragma unroll
        for (int m = 1; m < 32; m <<= 1) ss += __shfl_xor(ss, m);
        scale = rsqrtf(ss);
    }
    uint2 pack;
    pack.x = (unsigned)f2bf(v.x * scale) | ((unsigned)f2bf(v.y * scale) << 16);
    pack.y = (unsigned)f2bf(v.z * scale) | ((unsigned)f2bf(v.w * scale) << 16);
    *(uint2*)(dst + l32 * 4) = pack;
}

// Pass B: fused bf16 GEMM + per-row max over negatives.
// 1-D grid of 2000 blocks, XCD-swizzled so each XCD owns a contiguous chunk of
// slabs with all 8 row-groups -> B slab is L2-resident per XCD.
// Block = 4 waves; wave owns 64 rows (4 x 16-row subtiles). Depth-4 register
// prefetch of B (static buffer indexing).
__global__ __launch_bounds__(256, 2) void gemmmax_kernel(
        const unsigned short* __restrict__ en,
        const unsigned short* __restrict__ pn,
        const int* __restrict__ labels,
        unsigned int* __restrict__ minneg) {
    // XCD swizzle: assume block n dispatches to XCD n%8; give XCD x the
    // contiguous work range [x*chunk, (x+1)*chunk).
    int n = blockIdx.x;
    int chunk = gridDim.x >> 3;            // 2000/8 = 250
    int wgid = (n & 7) * chunk + (n >> 3);
    int slab   = wgid >> 3;                // /ROWG
    int rowgrp = wgid & (ROWG - 1);

    int lane = threadIdx.x & 63;
    int wid  = threadIdx.x >> 6;
    int wbase = rowgrp * 256 + wid * 64;
    int r16 = lane & 15;
    int g   = lane >> 4;
    int col0 = slab * SLAB;

    // A fragments: lane l, slot j -> E[row = wbase+s4*16+(l&15)][k = k4*32 + (l>>4)*8 + j]
    bf16x8 a[4][4];
    #pragma unroll
    for (int s4 = 0; s4 < 4; ++s4)
        #pragma unroll
        for (int k4 = 0; k4 < 4; ++k4)
            a[s4][k4] = *(const bf16x8*)(en + (size_t)(wbase + s4 * 16 + r16) * D + k4 * 32 + g * 8);

    // Wave-uniform bitmask of steps containing a positive class for this wave's rows.
    unsigned bits = 0;
    #pragma unroll
    for (int s4 = 0; s4 < 4; ++s4)
        #pragma unroll
        for (int i = 0; i < 4; ++i) {
            int lb = labels[wbase + s4 * 16 + g * 4 + i];
            int pc = lb - col0;
            if (pc >= 0 && pc < SLAB) bits |= 1u << (pc >> 4);
        }
    #pragma unroll
    for (int m = 1; m < 64; m <<= 1) bits |= __shfl_xor(bits, m);
    unsigned sbits = __builtin_amdgcn_readfirstlane(bits);

    float rm[4][4];
    #pragma unroll
    for (int s4 = 0; s4 < 4; ++s4)
        #pragma unroll
        for (int i = 0; i < 4; ++i) rm[s4][i] = -1e30f;

    const unsigned short* pbase = pn + (size_t)(col0 + r16) * D + g * 8;

    bf16x8 bA[4], bB[4], bC[4], bD[4];

#define LOADB(BUF, STEP)                                                        \
    {                                                                           \
        _Pragma("unroll")                                                       \
        for (int j = 0; j < 4; ++j)                                             \
            BUF[j] = *(const bf16x8*)(pbase + (size_t)(STEP) * (16 * D) + 32 * j); \
    }

#define COMPUTE(BUF, STEP)                                                      \
    {                                                                           \
        f32x4 acc[4];                                                           \
        _Pragma("unroll")                                                       \
        for (int s4 = 0; s4 < 4; ++s4) acc[s4] = (f32x4){0.f, 0.f, 0.f, 0.f};   \
        _Pragma("unroll")                                                       \
        for (int j = 0; j < 4; ++j) {                                           \
            _Pragma("unroll")                                                   \
            for (int s4 = 0; s4 < 4; ++s4)                                      \
                acc[s4] = __builtin_amdgcn_mfma_f32_16x16x32_bf16(              \
                    a[s4][j], BUF[j], acc[s4], 0, 0, 0);                        \
        }                                                                       \
        if ((sbits >> (STEP)) & 1u) {  /* rare: positive class in this step */  \
            int colg = col0 + (STEP) * 16 + r16;                                \
            _Pragma("unroll")                                                   \
            for (int s4 = 0; s4 < 4; ++s4)                                      \
                _Pragma("unroll")                                               \
                for (int i = 0; i < 4; ++i) {                                   \
                    int lb = labels[wbase + s4 * 16 + g * 4 + i];               \
                    float v = (colg == lb) ? -1e30f : acc[s4][i];               \
                    rm[s4][i] = fmaxf(rm[s4][i], v);                            \
                }                                                               \
        } else {                                                                \
            _Pragma("unroll")                                                   \
            for (int s4 = 0; s4 < 4; ++s4)                                      \
                _Pragma("unroll")                                               \
                for (int i = 0; i < 4; ++i)                                     \
                    rm[s4][i] = fmaxf(rm[s4][i], acc[s4][i]);                   \
        }                                                                       \
    }

    // prologue: steps 0..3 in flight
    LOADB(bA, 0) LOADB(bB, 1) LOADB(bC, 2) LOADB(bD, 3)

    int s = 0;
    #pragma unroll 1
    for (; s + 8 <= SPB; s += 4) {        // s = 0,4,8,12,16  (SPB=25)
        COMPUTE(bA, s)     LOADB(bA, s + 4)
        COMPUTE(bB, s + 1) LOADB(bB, s + 5)
        COMPUTE(bC, s + 2) LOADB(bC, s + 6)
        COMPUTE(bD, s + 3) LOADB(bD, s + 7)
    }
    // s == 20: steps 20..23 in bA..bD; step 24 still to load.
    COMPUTE(bA, s)     LOADB(bA, s + 4)
    COMPUTE(bB, s + 1)
    COMPUTE(bC, s + 2)
    COMPUTE(bD, s + 3)
    COMPUTE(bA, s + 4)
#undef LOADB
#undef COMPUTE

    // reduce max across the 16 lanes of each row-group, then combine across blocks
    #pragma unroll
    for (int s4 = 0; s4 < 4; ++s4)
        #pragma unroll
        for (int i = 0; i < 4; ++i) {
            float v = rm[s4][i];
            v = fmaxf(v, __shfl_xor(v, 1));
            v = fmaxf(v, __shfl_xor(v, 2));
            v = fmaxf(v, __shfl_xor(v, 4));
            v = fmaxf(v, __shfl_xor(v, 8));
            if (r16 == 0) {
                int r = wbase + s4 * 16 + g * 4 + i;
                float md = fmaxf(2.f - 2.f * v, 0.f);  // >=0 -> uint order == float order
                atomicMin(minneg + r, __float_as_uint(md));
            }
        }
}

// Pass C: exact fp32 positive distance + per-row loss, accumulate sum.
__global__ void finalize_kernel(const float* __restrict__ emb,
                                const float* __restrict__ prox,
                                const int* __restrict__ labels,
                                const unsigned int* __restrict__ minneg,
                                float* __restrict__ accum, int B) {
    int wave = blockIdx.x * (blockDim.x >> 6) + (threadIdx.x >> 6);
    int lane = threadIdx.x & 63;
    if (wave >= B) return;
    int lab = labels[wave];
    float2 e = *(const float2*)(emb + (size_t)wave * D + lane * 2);
    float2 p = *(const float2*)(prox + (size_t)lab * D + lane * 2);
    float spp = p.x * p.x + p.y * p.y;
    float sep = e.x * p.x + e.y * p.y;
    #pragma unroll
    for (int m = 1; m < 64; m <<= 1) {
        spp += __shfl_xor(spp, m);
        sep += __shfl_xor(sep, m);
    }
    if (lane == 0) {
        float pos_sim = sep * rsqrtf(spp);
        float pos_dist = 2.f - 2.f * pos_sim;
        float mn = __uint_as_float(minneg[wave]);
        float loss = fmaxf(pos_dist + LOSS_MARGIN - mn, 0.f);
        atomicAdd(accum, loss);
    }
}

__global__ void writeout_kernel(const float* __restrict__ accum,
                                float* __restrict__ out, float invB) {
    out[0] = accum[0] * invB;
}

extern "C" void kernel_launch(void* const* d_in, const int* in_sizes, int n_in,
                              void* d_out, int out_size, void* d_ws, size_t ws_size,
                              hipStream_t stream) {
    const float* emb  = (const float*)d_in[0];
    const float* prox = (const float*)d_in[1];
    const int*   labels = (const int*)d_in[2];
    int B = in_sizes[0] / D;  // 2048
    int C = in_sizes[1] / D;  // 100000

    char* ws = (char*)d_ws;
    unsigned short* pn = (unsigned short*)ws;                       // C*D bf16 = 25.6 MB
    size_t offEN  = (size_t)C * D * 2 + (size_t)64 * D * 2;         // +64 pad rows
    unsigned short* en = (unsigned short*)(ws + offEN);             // B*D bf16
    size_t offMIN = offEN + (size_t)B * D * 2;
    unsigned int* minneg = (unsigned int*)(ws + offMIN);            // B u32
    size_t offACC = offMIN + (size_t)B * 4;
    float* accum = (float*)(ws + offACC);                           // 1 f32

    int totalRows = C + B;
    int prepWaves = (totalRows + 1) / 2;
    prep_kernel<<<dim3((prepWaves + 3) / 4), dim3(256), 0, stream>>>(prox, emb, pn, en, minneg, accum, C, B);
    gemmmax_kernel<<<dim3((B / 256) * (C / SLAB)), dim3(256), 0, stream>>>(en, pn, labels, minneg);
    finalize_kernel<<<dim3((B + 3) / 4), dim3(256), 0, stream>>>(emb, prox, labels, minneg, accum, B);
    writeout_kernel<<<dim3(1), dim3(1), 0, stream>>>(accum, (float*)d_out, 1.f / (float)B);
}

// Round 5
// 179.362 us; speedup vs baseline: 1.9693x; 1.2828x over previous
//
#include <hip/hip_runtime.h>
#include <hip/hip_bf16.h>

#define D 128
#define LOSS_MARGIN 0.2f
#define SPB 25                 // 16-col MFMA steps per block
#define SLAB (SPB * 16)        // 400 cols; C = 250 slabs * 400
#define ROWG 8                 // 2048 / 256 row-groups
#define CHUNK_BYTES 20480      // 80 cols * 256 B
#define NCHUNK 5               // 5 chunks * 5 steps = 25 steps

typedef __attribute__((ext_vector_type(8))) short bf16x8;
typedef __attribute__((ext_vector_type(4))) float f32x4;

static __device__ __forceinline__ unsigned short f2bf(float f) {
    unsigned u = __float_as_uint(f);
    unsigned r = (u + 0x7FFFu + ((u >> 16) & 1u)) >> 16;  // RNE
    return (unsigned short)r;
}

// async global->LDS, 16B per lane; LDS dest must be wave-uniform base.
static __device__ __forceinline__ void stage16(const void* g, void* l) {
    __builtin_amdgcn_global_load_lds(
        (__attribute__((address_space(1))) void*)g,
        (__attribute__((address_space(3))) void*)l, 16, 0, 0);
}

// Pass A: L2-normalize proxies -> bf16 (XOR-swizzled rows) ; embeddings -> bf16 (linear).
// Swizzle: within each 256B row, 16B slot at byte b stored at b ^ ((row&7)<<4).
// Also initializes minneg sentinels and the loss accumulator.
__global__ void prep_kernel(const float* __restrict__ prox,
                            const float* __restrict__ emb,
                            unsigned short* __restrict__ pn,
                            unsigned short* __restrict__ en,
                            unsigned int* __restrict__ minneg,
                            float* __restrict__ accum,
                            int C, int B) {
    unsigned gtid = blockIdx.x * blockDim.x + threadIdx.x;
    if (gtid < (unsigned)B) minneg[gtid] = 0xFFFFFFFFu;
    if (gtid == 0) *accum = 0.f;

    int wave = blockIdx.x * (blockDim.x >> 6) + (threadIdx.x >> 6);
    int lane = threadIdx.x & 63;
    int half = lane >> 5;
    int l32  = lane & 31;
    int row = wave * 2 + half;
    if (row >= C + B) return;

    if (row < C) {
        float4 v = *(const float4*)(prox + (size_t)row * D + l32 * 4);
        float ss = v.x * v.x + v.y * v.y + v.z * v.z + v.w * v.w;
        #pragma unroll
        for (int m = 1; m < 32; m <<= 1) ss += __shfl_xor(ss, m);
        float scale = rsqrtf(ss);
        uint2 pack;
        pack.x = (unsigned)f2bf(v.x * scale) | ((unsigned)f2bf(v.y * scale) << 16);
        pack.y = (unsigned)f2bf(v.z * scale) | ((unsigned)f2bf(v.w * scale) << 16);
        unsigned off = (unsigned)(l32 * 8) ^ (((unsigned)row & 7u) << 4);
        *(uint2*)((char*)(pn + (size_t)row * D) + off) = pack;
    } else {
        int r = row - C;
        float4 v = *(const float4*)(emb + (size_t)r * D + l32 * 4);
        uint2 pack;
        pack.x = (unsigned)f2bf(v.x) | ((unsigned)f2bf(v.y) << 16);
        pack.y = (unsigned)f2bf(v.z) | ((unsigned)f2bf(v.w) << 16);
        *(uint2*)(en + (size_t)r * D + l32 * 4) = pack;
    }
}

// Pass B: fused bf16 GEMM + per-row max over negatives.
// XCD-swizzled 1-D grid (2000 blocks). Block = 4 waves, 256 rows; slab = 400 cols.
// B staged via global_load_lds into double-buffered LDS chunks (80 cols each),
// one barrier per chunk (m97 structure). ds_read_b128 with XOR-swizzle.
__global__ __launch_bounds__(256, 2) void gemmmax_kernel(
        const unsigned short* __restrict__ en,
        const unsigned short* __restrict__ pn,
        const int* __restrict__ labels,
        unsigned int* __restrict__ minneg) {
    __shared__ char smem[2 * CHUNK_BYTES];   // 40 KiB

    int n = blockIdx.x;
    int chunkg = gridDim.x >> 3;             // 2000/8 = 250 per XCD
    int wgid = (n & 7) * chunkg + (n >> 3);
    int slab   = wgid >> 3;
    int rowgrp = wgid & (ROWG - 1);

    int lane = threadIdx.x & 63;
    int wid  = threadIdx.x >> 6;
    int wbase = rowgrp * 256 + wid * 64;
    int r16 = lane & 15;
    int g   = lane >> 4;
    int col0 = slab * SLAB;
    int swz = (r16 & 7) << 4;

    const char* slabSrc = (const char*)pn + (size_t)col0 * (D * 2);

    // stage chunk 0 into buf 0 (each wave stages its 1KB per round)
    {
        const char* gs = slabSrc;
        char* ls = smem;
        #pragma unroll
        for (int r = 0; r < 5; ++r)
            stage16(gs + r * 4096 + wid * 1024 + lane * 16,
                    ls + r * 4096 + wid * 1024);
    }

    // A fragments (overlap with stage flight):
    // lane l, slot j -> E[row = wbase+s4*16+(l&15)][k = k4*32 + (l>>4)*8 + j]
    bf16x8 a[4][4];
    #pragma unroll
    for (int s4 = 0; s4 < 4; ++s4)
        #pragma unroll
        for (int k4 = 0; k4 < 4; ++k4)
            a[s4][k4] = *(const bf16x8*)(en + (size_t)(wbase + s4 * 16 + r16) * D + k4 * 32 + g * 8);

    // wave-uniform bitmask of steps containing a positive class
    unsigned bits = 0;
    #pragma unroll
    for (int s4 = 0; s4 < 4; ++s4)
        #pragma unroll
        for (int i = 0; i < 4; ++i) {
            int lb = labels[wbase + s4 * 16 + g * 4 + i];
            int pc = lb - col0;
            if (pc >= 0 && pc < SLAB) bits |= 1u << (pc >> 4);
        }
    #pragma unroll
    for (int m = 1; m < 64; m <<= 1) bits |= __shfl_xor(bits, m);
    unsigned sbits = __builtin_amdgcn_readfirstlane(bits);

    float rm[4][4];
    #pragma unroll
    for (int s4 = 0; s4 < 4; ++s4)
        #pragma unroll
        for (int i = 0; i < 4; ++i) rm[s4][i] = -1e30f;

    __syncthreads();   // drains vmcnt -> chunk 0 resident

    int cur = 0;
    #pragma unroll 1
    for (int t = 0; t < NCHUNK; ++t) {
        if (t + 1 < NCHUNK) {  // stage next chunk into the other buffer
            const char* gs = slabSrc + (size_t)(t + 1) * CHUNK_BYTES;
            char* ls = smem + (cur ^ 1) * CHUNK_BYTES;
            #pragma unroll
            for (int r = 0; r < 5; ++r)
                stage16(gs + r * 4096 + wid * 1024 + lane * 16,
                        ls + r * 4096 + wid * 1024);
        }
        const char* lrow = smem + cur * CHUNK_BYTES + r16 * 256;
        #pragma unroll
        for (int c16 = 0; c16 < 5; ++c16) {
            int step = t * 5 + c16;
            const char* lb = lrow + c16 * 4096;
            bf16x8 b0 = *(const bf16x8*)(lb + ((g * 16 + 0)   ^ swz));
            bf16x8 b1 = *(const bf16x8*)(lb + ((g * 16 + 64)  ^ swz));
            bf16x8 b2 = *(const bf16x8*)(lb + ((g * 16 + 128) ^ swz));
            bf16x8 b3 = *(const bf16x8*)(lb + ((g * 16 + 192) ^ swz));
            f32x4 acc[4];
            #pragma unroll
            for (int s4 = 0; s4 < 4; ++s4) acc[s4] = (f32x4){0.f, 0.f, 0.f, 0.f};
            #pragma unroll
            for (int s4 = 0; s4 < 4; ++s4)
                acc[s4] = __builtin_amdgcn_mfma_f32_16x16x32_bf16(a[s4][0], b0, acc[s4], 0, 0, 0);
            #pragma unroll
            for (int s4 = 0; s4 < 4; ++s4)
                acc[s4] = __builtin_amdgcn_mfma_f32_16x16x32_bf16(a[s4][1], b1, acc[s4], 0, 0, 0);
            #pragma unroll
            for (int s4 = 0; s4 < 4; ++s4)
                acc[s4] = __builtin_amdgcn_mfma_f32_16x16x32_bf16(a[s4][2], b2, acc[s4], 0, 0, 0);
            #pragma unroll
            for (int s4 = 0; s4 < 4; ++s4)
                acc[s4] = __builtin_amdgcn_mfma_f32_16x16x32_bf16(a[s4][3], b3, acc[s4], 0, 0, 0);

            if ((sbits >> step) & 1u) {  // rare: positive class in this step
                int colg = col0 + step * 16 + r16;
                #pragma unroll
                for (int s4 = 0; s4 < 4; ++s4)
                    #pragma unroll
                    for (int i = 0; i < 4; ++i) {
                        int lb2 = labels[wbase + s4 * 16 + g * 4 + i];
                        float v = (colg == lb2) ? -1e30f : acc[s4][i];
                        rm[s4][i] = fmaxf(rm[s4][i], v);
                    }
            } else {
                #pragma unroll
                for (int s4 = 0; s4 < 4; ++s4)
                    #pragma unroll
                    for (int i = 0; i < 4; ++i)
                        rm[s4][i] = fmaxf(rm[s4][i], acc[s4][i]);
            }
        }
        __syncthreads();   // drains stage(t+1); buf[cur] free for reuse
        cur ^= 1;
    }

    // reduce max across the 16 lanes of each row-group, combine across blocks
    #pragma unroll
    for (int s4 = 0; s4 < 4; ++s4)
        #pragma unroll
        for (int i = 0; i < 4; ++i) {
            float v = rm[s4][i];
            v = fmaxf(v, __shfl_xor(v, 1));
            v = fmaxf(v, __shfl_xor(v, 2));
            v = fmaxf(v, __shfl_xor(v, 4));
            v = fmaxf(v, __shfl_xor(v, 8));
            if (r16 == 0) {
                int r = wbase + s4 * 16 + g * 4 + i;
                float md = fmaxf(2.f - 2.f * v, 0.f);  // >=0 -> uint order == float order
                atomicMin(minneg + r, __float_as_uint(md));
            }
        }
}

// Pass C: exact fp32 positive distance + per-row loss, accumulate sum.
__global__ void finalize_kernel(const float* __restrict__ emb,
                                const float* __restrict__ prox,
                                const int* __restrict__ labels,
                                const unsigned int* __restrict__ minneg,
                                float* __restrict__ accum, int B) {
    int wave = blockIdx.x * (blockDim.x >> 6) + (threadIdx.x >> 6);
    int lane = threadIdx.x & 63;
    if (wave >= B) return;
    int lab = labels[wave];
    float2 e = *(const float2*)(emb + (size_t)wave * D + lane * 2);
    float2 p = *(const float2*)(prox + (size_t)lab * D + lane * 2);
    float spp = p.x * p.x + p.y * p.y;
    float sep = e.x * p.x + e.y * p.y;
    #pragma unroll
    for (int m = 1; m < 64; m <<= 1) {
        spp += __shfl_xor(spp, m);
        sep += __shfl_xor(sep, m);
    }
    if (lane == 0) {
        float pos_sim = sep * rsqrtf(spp);
        float pos_dist = 2.f - 2.f * pos_sim;
        float mn = __uint_as_float(minneg[wave]);
        float loss = fmaxf(pos_dist + LOSS_MARGIN - mn, 0.f);
        atomicAdd(accum, loss);
    }
}

__global__ void writeout_kernel(const float* __restrict__ accum,
                                float* __restrict__ out, float invB) {
    out[0] = accum[0] * invB;
}

extern "C" void kernel_launch(void* const* d_in, const int* in_sizes, int n_in,
                              void* d_out, int out_size, void* d_ws, size_t ws_size,
                              hipStream_t stream) {
    const float* emb  = (const float*)d_in[0];
    const float* prox = (const float*)d_in[1];
    const int*   labels = (const int*)d_in[2];
    int B = in_sizes[0] / D;  // 2048
    int C = in_sizes[1] / D;  // 100000

    char* ws = (char*)d_ws;
    unsigned short* pn = (unsigned short*)ws;                       // C*D bf16 (swizzled rows)
    size_t offEN  = (size_t)C * D * 2 + (size_t)64 * D * 2;
    unsigned short* en = (unsigned short*)(ws + offEN);             // B*D bf16
    size_t offMIN = offEN + (size_t)B * D * 2;
    unsigned int* minneg = (unsigned int*)(ws + offMIN);            // B u32
    size_t offACC = offMIN + (size_t)B * 4;
    float* accum = (float*)(ws + offACC);                           // 1 f32

    int totalRows = C + B;
    int prepWaves = (totalRows + 1) / 2;
    prep_kernel<<<dim3((prepWaves + 3) / 4), dim3(256), 0, stream>>>(prox, emb, pn, en, minneg, accum, C, B);
    gemmmax_kernel<<<dim3((B / 256) * (C / SLAB)), dim3(256), 0, stream>>>(en, pn, labels, minneg);
    finalize_kernel<<<dim3((B + 3) / 4), dim3(256), 0, stream>>>(emb, prox, labels, minneg, accum, B);
    writeout_kernel<<<dim3(1), dim3(1), 0, stream>>>(accum, (float*)d_out, 1.f / (float)B);
}